// Round 2
// baseline (40751.685 us; speedup 1.0000x reference)
//
#include <hip/hip_runtime.h>
#include <hip/hip_bf16.h>
#include <stdint.h>

#define T_STEPS 1024
#define NBLK    32      // recurrent blocks; each owns 16 consecutive hidden cols
#define NTHR    256

typedef __attribute__((ext_vector_type(8))) short short8;
typedef __attribute__((ext_vector_type(4))) float float4v;
typedef unsigned short ushort_t;

__device__ __forceinline__ ushort_t f2bf(float f) {
    __hip_bfloat16 h = __float2bfloat16(f);  // RNE
    return __builtin_bit_cast(ushort_t, h);
}

// ---------------------------------------------------------------------------
// Setup: WiT/WhT = bf16 transpose [2048][512]; ring slot1 = h0 (new layout);
// flags[32] = 0.
// ---------------------------------------------------------------------------
__global__ void lstm_setup(const float* __restrict__ Wi,
                           const float* __restrict__ Wh,
                           const float* __restrict__ h0,
                           ushort_t* __restrict__ WiT,
                           ushort_t* __restrict__ WhT,
                           ushort_t* __restrict__ ring,
                           unsigned int* __restrict__ flag) {
    size_t i = (size_t)blockIdx.x * NTHR + threadIdx.x;
    if (i < 1048576) {
        size_t c = i >> 9, k = i & 511;
        WiT[i] = f2bf(Wi[k * 2048 + c]);
    } else if (i < 2097152) {
        size_t j = i - 1048576;
        size_t c = j >> 9, k = j & 511;
        WhT[j] = f2bf(Wh[k * 2048 + c]);
    } else if (i < 2129920) {
        size_t j = i - 2097152;              // slot1: [blk(32)][row(64)][col(16)]
        size_t blk = j >> 10, row = (j >> 4) & 63, col = j & 15;
        ring[32768 + j] = f2bf(h0[row * 512 + blk * 16 + col]);
    } else if (i < 2129952) {
        flag[i - 2129920] = 0u;
    }
}

// ---------------------------------------------------------------------------
// Persistent recurrent kernel. 32 blocks x 256 threads (1 block/CU, 1 wave/SIMD
// -> 512-VGPR budget/wave; weight frags stay in registers).
// Block owns hidden cols [blk*16, blk*16+16). Wave = gate g; lanes: l15 = local
// col, quad = k-subgroup; 4 mi row-tiles per wave.
// MFMA 16x16x32 bf16:
//   A-frag: lane holds A[m=l15][k=quad*8 + j]
//   B-frag: lane holds B[k=quad*8 + j][n=l15]
//   C/D:    reg r = D[row=quad*4+r][col=l15]
// Sync: per-block flag[blk]=t+1 (release store, all 32 flags in ONE cacheline);
// consumers poll relaxed + one acquire fence per step. No RMW atomics.
// ---------------------------------------------------------------------------
__global__ __launch_bounds__(NTHR, 1) void lstm_persist(
    const float* __restrict__ X,        // [1024][64][512] fp32
    const float* __restrict__ c0,       // [64][512]
    const float* __restrict__ bias,     // [2048]
    const ushort_t* __restrict__ WiT,   // [2048][512] bf16
    const ushort_t* __restrict__ WhT,   // [2048][512] bf16
    ushort_t* __restrict__ ring,        // [2][32*64*16] bf16
    unsigned int* __restrict__ flag,    // [32], one line
    float* __restrict__ out)            // ys | cT | hT
{
    const int blk  = blockIdx.x;
    const int tid  = threadIdx.x;
    const int lane = tid & 63;
    const int g    = tid >> 6;            // wave = gate (0:i 1:f 2:g 3:o)
    const int l15  = lane & 15;
    const int quad = lane >> 4;

    // 64 KB LDS: h stage [64 rows][512 bf16], 16B chunks XOR-swizzled by row&15.
    // After B3 the first 18496 B are reused as ztile[4][64][17] fp32; hout
    // [64][16] bf16 lives at +18496 (barrier-protected overlays).
    __shared__ alignas(16) char smem[65536];
    float*    ztile = (float*)smem;
    ushort_t* hout  = (ushort_t*)(smem + 18496);

    // --- weight fragments in registers: z-col = g*512 + blk*16 + l15 ---
    const int col = g * 512 + blk * 16 + l15;
    short8 wib[16], whb[16];
    {
        const short8* wp = (const short8*)(WiT + (size_t)col * 512);
        const short8* hp = (const short8*)(WhT + (size_t)col * 512);
#pragma unroll
        for (int kk = 0; kk < 16; kk++) {
            wib[kk] = wp[kk * 4 + quad];   // k = kk*32 + quad*8 .. +7
            whb[kk] = hp[kk * 4 + quad];
        }
    }
    const float bval = bias[col];

    // gate-phase role: col gcol, rows grow0..grow0+3; cell state in registers
    const int gcol  = tid & 15;
    const int grow0 = (tid >> 4) * 4;
    float c_reg[4];
#pragma unroll
    for (int j = 0; j < 4; j++)
        c_reg[j] = c0[(grow0 + j) * 512 + blk * 16 + gcol];

    for (int t = 0; t < T_STEPS; t++) {
        // ---- x_t @ Wi for 4 row-tiles (overlaps producer->consumer skew) ----
        float4v acc[4];
#pragma unroll
        for (int mi = 0; mi < 4; mi++) {
            float4v a4 = {bval, bval, bval, bval};
            acc[mi] = a4;
            const float* xbase = X + ((size_t)t * 64 + mi * 16 + l15) * 512;
#pragma unroll
            for (int kk = 0; kk < 16; kk++) {
                float4v x0 = *(const float4v*)(xbase + kk * 32 + quad * 8);
                float4v x1 = *(const float4v*)(xbase + kk * 32 + quad * 8 + 4);
                short8 a;
                a[0] = (short)f2bf(x0.x); a[1] = (short)f2bf(x0.y);
                a[2] = (short)f2bf(x0.z); a[3] = (short)f2bf(x0.w);
                a[4] = (short)f2bf(x1.x); a[5] = (short)f2bf(x1.y);
                a[6] = (short)f2bf(x1.z); a[7] = (short)f2bf(x1.w);
                acc[mi] = __builtin_amdgcn_mfma_f32_16x16x32_bf16(a, wib[kk], acc[mi], 0, 0, 0);
            }
        }

        // ---- wait for all blocks' h_{t-1}: relaxed poll of one flag line ----
        if (t > 0 && tid < 64) {
            const unsigned target = (unsigned)t;
            for (;;) {
                unsigned v = (lane < NBLK)
                    ? __hip_atomic_load(&flag[lane], __ATOMIC_RELAXED,
                                        __HIP_MEMORY_SCOPE_AGENT)
                    : target;
                if (__ballot(v >= target) == ~0ull) break;
                __builtin_amdgcn_s_sleep(1);
            }
        }
        __syncthreads();   // B1
        __builtin_amdgcn_fence(__ATOMIC_ACQUIRE, "agent");  // one inv per step

        // ---- stage h_{t-1}: ring [blk'][row][16] bf16 -> swizzled LDS ----
        const uint4* rsl = (const uint4*)(ring + (size_t)((t + 1) & 1) * 32768);
#pragma unroll
        for (int i = 0; i < 16; i++) {
            int f   = i * 256 + tid;           // 16B chunk id, 0..4095
            uint4 v = rsl[f];
            int row = (f >> 1) & 63;
            int cj  = ((f >> 7) << 1) | (f & 1);   // hidden 8-col chunk 0..63
            *(uint4*)(smem + row * 1024 + ((cj ^ (row & 15)) * 16)) = v;
        }
        __syncthreads();   // B2

        // ---- h_{t-1} @ Wh ----
#pragma unroll
        for (int mi = 0; mi < 4; mi++) {
            const int row = mi * 16 + l15;
#pragma unroll
            for (int kk = 0; kk < 16; kk++) {
                int ch   = (kk * 4 + quad) ^ l15;
                short8 a = *(const short8*)(smem + row * 1024 + ch * 16);
                acc[mi] = __builtin_amdgcn_mfma_f32_16x16x32_bf16(a, whb[kk], acc[mi], 0, 0, 0);
            }
        }
        __syncthreads();   // B3: h fully consumed; ztile overlay now safe

        // ---- scatter z: ztile[g][row][col] ----
#pragma unroll
        for (int mi = 0; mi < 4; mi++)
#pragma unroll
            for (int r = 0; r < 4; r++)
                ztile[g * 1088 + (mi * 16 + quad * 4 + r) * 17 + l15] = acc[mi][r];
        __syncthreads();   // B4

        // ---- gates: 4 cells per thread, c in registers ----
        float nh[4];
#pragma unroll
        for (int j = 0; j < 4; j++) {
            int row  = grow0 + j;
            float zi = ztile[0 * 1088 + row * 17 + gcol];
            float zf = ztile[1 * 1088 + row * 17 + gcol];
            float zg = ztile[2 * 1088 + row * 17 + gcol];
            float zo = ztile[3 * 1088 + row * 17 + gcol];
            float si = 1.f / (1.f + __expf(-zi));
            float sf = 1.f / (1.f + __expf(-zf));
            float tg = tanhf(zg);
            float so = 1.f / (1.f + __expf(-zo));
            float nc = sf * c_reg[j] + si * tg;
            nh[j]    = so * tanhf(nc);
            c_reg[j] = nc;
            hout[row * 16 + gcol] = f2bf(nh[j]);
        }
        __syncthreads();   // B5: hout visible

        // ---- publish h_t: contiguous 2 KB ring burst, then release flag ----
        {
            ushort_t* wbase = ring + (size_t)(t & 1) * 32768 + blk * 1024;
            *(uint2*)(wbase + tid * 4) = *(const uint2*)(hout + tid * 4);
        }
        __syncthreads();   // B6: ring stores drained to L2 (vmcnt(0) per wave)
        if (tid == 0)
            __hip_atomic_store(&flag[blk], (unsigned)(t + 1), __ATOMIC_RELEASE,
                               __HIP_MEMORY_SCOPE_AGENT);

        // ---- ys stores off the critical path ----
#pragma unroll
        for (int j = 0; j < 4; j++)
            out[(size_t)t * 32768 + (grow0 + j) * 512 + blk * 16 + gcol] = nh[j];
        if (t == T_STEPS - 1) {
#pragma unroll
            for (int j = 0; j < 4; j++) {
                out[33554432u + (grow0 + j) * 512 + blk * 16 + gcol] = c_reg[j];
                out[33554432u + 32768u + (grow0 + j) * 512 + blk * 16 + gcol] = nh[j];
            }
        }
    }
}

// ---------------------------------------------------------------------------
extern "C" void kernel_launch(void* const* d_in, const int* in_sizes, int n_in,
                              void* d_out, int out_size, void* d_ws, size_t ws_size,
                              hipStream_t stream) {
    const float* X    = (const float*)d_in[0];   // [1024][64][512]
    const float* c0   = (const float*)d_in[1];   // [64][512]
    const float* h0   = (const float*)d_in[2];   // [64][512]
    const float* Wi   = (const float*)d_in[3];   // [512][2048]
    const float* Wh   = (const float*)d_in[4];   // [512][2048]
    const float* bias = (const float*)d_in[5];   // [2048]

    char* ws = (char*)d_ws;
    ushort_t*     WiT  = (ushort_t*)ws;                    // 2,097,152 B
    ushort_t*     WhT  = (ushort_t*)(ws + 2097152);        // 2,097,152 B
    ushort_t*     ring = (ushort_t*)(ws + 4194304);        //   131,072 B
    unsigned int* flag = (unsigned int*)(ws + 4325376);    //       128 B
    // total ws need: 4,325,504 B

    lstm_setup<<<8321, NTHR, 0, stream>>>(Wi, Wh, h0, WiT, WhT, ring, flag);
    lstm_persist<<<NBLK, NTHR, 0, stream>>>(X, c0, bias, WiT, WhT, ring, flag,
                                            (float*)d_out);
}

// Round 3
// 7009.298 us; speedup vs baseline: 5.8139x; 5.8139x over previous
//
#include <hip/hip_runtime.h>
#include <hip/hip_bf16.h>
#include <stdint.h>

#define T_STEPS 1024
#define NBLK    64      // recurrent blocks; each owns 8 consecutive hidden cols
#define NTHR    512     // 8 waves: wave = (mi = w>>1, nt = w&1)

typedef __attribute__((ext_vector_type(8))) short short8;
typedef __attribute__((ext_vector_type(4))) float float4v;
typedef unsigned short ushort_t;
typedef unsigned long long ull;
typedef unsigned int u32;

__device__ __forceinline__ ushort_t f2bf(float f) {
    __hip_bfloat16 h = __float2bfloat16(f);  // RNE
    return __builtin_bit_cast(ushort_t, h);
}

// ---------------------------------------------------------------------------
// Setup: WiT/WhT = bf16 transpose [2048][512]; ring slot1 = h0 in [ch][row][8]
// layout; flag region (2 KB) = 0.
// ---------------------------------------------------------------------------
__global__ void lstm_setup(const float* __restrict__ Wi,
                           const float* __restrict__ Wh,
                           const float* __restrict__ h0,
                           ushort_t* __restrict__ WiT,
                           ushort_t* __restrict__ WhT,
                           ushort_t* __restrict__ ring,
                           u32* __restrict__ flag) {
    size_t i = (size_t)blockIdx.x * NTHR + threadIdx.x;
    if (i < 1048576) {
        size_t c = i >> 9, k = i & 511;
        WiT[i] = f2bf(Wi[k * 2048 + c]);
    } else if (i < 2097152) {
        size_t j = i - 1048576;
        size_t c = j >> 9, k = j & 511;
        WhT[j] = f2bf(Wh[k * 2048 + c]);
    } else if (i < 2129920) {
        size_t j = i - 2097152;          // slot1: [ch(64)][row(64)][c(8)]
        size_t ch = j >> 9, row = (j >> 3) & 63, c = j & 7;
        ring[32768 + j] = f2bf(h0[row * 512 + ch * 8 + c]);
    } else if (i < 2130432) {
        flag[i - 2129920] = 0u;
    }
}

// ---------------------------------------------------------------------------
// Persistent recurrent kernel: 64 blocks x 512 threads.
// Block owns hidden cols [blk*8, blk*8+8) -> 16 z-cols (4 gates x 4 cols per
// n-tile, 2 n-tiles). Wave w: mi = w>>1 (16 rows), nt = w&1 (4 hidden cols,
// all 4 gates in-tile: l15 -> g = l15>>2, c = l15&3).
// LDS A-buffer: [ch(64)][row(64)][16B] bf16 — conflict-free for b128 A-frag
// reads AND matches global_load_lds lane order. Reused for x_t then h_{t-1}.
// Sync: NO fences. Ring/flags via relaxed agent atomics (sc0 sc1: targeted
// LLC write-through / bypass reads, no L2 wb/inv). h staged via
// global_load_lds aux=17 (sc0|sc1 -> coherent LLC read, direct to LDS).
// ---------------------------------------------------------------------------
__global__ __launch_bounds__(NTHR, 2) void lstm_persist(
    const float* __restrict__ X,        // [1024][64][512] fp32
    const float* __restrict__ c0,       // [64][512]
    const float* __restrict__ bias,     // [2048]
    const ushort_t* __restrict__ WiT,   // [2048][512] bf16
    const ushort_t* __restrict__ WhT,   // [2048][512] bf16
    ushort_t* __restrict__ ring,        // [2][64*64*8] bf16 ([ch][row][8])
    u32* __restrict__ flag,             // [64] spread at stride 8 words
    float* __restrict__ out)            // ys | cT | hT
{
    const int blk  = blockIdx.x;
    const int tid  = threadIdx.x;
    const int lane = tid & 63;
    const int w    = tid >> 6;
    const int l15  = lane & 15;
    const int quad = lane >> 4;
    const int nt   = w & 1;
    const int mi   = w >> 1;

    // 64 KB LDS A-buffer; after B4 first 9728 B reused: ztile_w (8 x 1088 B)
    // + hout_w (8 x 128 B at +8704). All overlays barrier-protected.
    __shared__ alignas(16) char smem[65536];

    // --- weight fragments in registers ---
    const int col = (l15 >> 2) * 512 + blk * 8 + nt * 4 + (l15 & 3);
    short8 wib[16], whb[16];
    {
        const short8* wp = (const short8*)(WiT + (size_t)col * 512);
        const short8* hp = (const short8*)(WhT + (size_t)col * 512);
#pragma unroll
        for (int kk = 0; kk < 16; kk++) {
            wib[kk] = wp[kk * 4 + quad];   // k = kk*32 + quad*8 .. +7
            whb[kk] = hp[kk * 4 + quad];
        }
    }
    const float bval = bias[col];

    // cell ownership: 512 threads <-> 64 rows x 8 cols, 1 cell each
    const int crow = mi * 16 + quad * 4 + (l15 >> 2);
    const int ccol = nt * 4 + (l15 & 3);          // local hidden col 0..7
    float c_reg = c0[crow * 512 + blk * 8 + ccol];

    // x-stage role: row = tid&63, seg = tid>>6 (64 cols of fp32 per thread)
    const int xrow = tid & 63;
    const int xseg = tid >> 6;

    float*    ztile_w = (float*)(smem + w * 1088);
    ushort_t* hout_w  = (ushort_t*)(smem + 8704 + w * 128);

    for (int t = 0; t < T_STEPS; t++) {
        // ---- stage x_t -> LDS bf16 [ch][row] (cached loads, L2 stays warm) --
        {
            const float* xb = X + (size_t)t * 32768 + xrow * 512 + xseg * 64;
#pragma unroll
            for (int jj = 0; jj < 8; jj++) {
                float4v a = *(const float4v*)(xb + jj * 8);
                float4v b = *(const float4v*)(xb + jj * 8 + 4);
                short8 p;
                p[0] = (short)f2bf(a.x); p[1] = (short)f2bf(a.y);
                p[2] = (short)f2bf(a.z); p[3] = (short)f2bf(a.w);
                p[4] = (short)f2bf(b.x); p[5] = (short)f2bf(b.y);
                p[6] = (short)f2bf(b.z); p[7] = (short)f2bf(b.w);
                *(short8*)(smem + (xseg * 8 + jj) * 1024 + xrow * 16) = p;
            }
        }
        __syncthreads();   // B1: x staged

        // ---- x_t @ Wi ----
        float4v acc = {bval, bval, bval, bval};
#pragma unroll
        for (int kk = 0; kk < 16; kk++) {
            short8 a = *(const short8*)(smem + (kk * 4 + quad) * 1024 +
                                        (mi * 16 + l15) * 16);
            acc = __builtin_amdgcn_mfma_f32_16x16x32_bf16(a, wib[kk], acc, 0, 0, 0);
        }

        // ---- wait for all h_{t-1} flags (relaxed LLC loads, no fences) ----
        if (t > 0 && w == 0) {
            const unsigned tgt = (unsigned)t;
            for (;;) {
                unsigned v = __hip_atomic_load(&flag[lane * 8], __ATOMIC_RELAXED,
                                               __HIP_MEMORY_SCOPE_AGENT);
                if (__ballot(v >= tgt) == ~0ull) break;
                __builtin_amdgcn_s_sleep(1);
            }
        }
        __syncthreads();   // B2: x consumed + h_{t-1} published everywhere

        // ---- stage h_{t-1}: ring -> LDS via global_load_lds (sc0|sc1=17) ----
        {
            const ushort_t* rslot = ring + (size_t)((t + 1) & 1) * 32768;
#pragma unroll
            for (int j = 0; j < 8; j++) {
                int f = w * 8 + j;
                const u32 __attribute__((address_space(1)))* gp =
                    (const u32 __attribute__((address_space(1)))*)(rslot + f * 512 + lane * 8);
                u32 __attribute__((address_space(3)))* lp =
                    (u32 __attribute__((address_space(3)))*)(smem + f * 1024);
                __builtin_amdgcn_global_load_lds(gp, lp, 16, 0, 17);
            }
        }
        __syncthreads();   // B3: h staged (vmcnt drained by barrier)

        // ---- h_{t-1} @ Wh ----
#pragma unroll
        for (int kk = 0; kk < 16; kk++) {
            short8 a = *(const short8*)(smem + (kk * 4 + quad) * 1024 +
                                        (mi * 16 + l15) * 16);
            acc = __builtin_amdgcn_mfma_f32_16x16x32_bf16(a, whb[kk], acc, 0, 0, 0);
        }
        __syncthreads();   // B4: h consumed; ztile/hout overlay now safe

        // ---- wave-private gate regroup (no cross-wave barrier needed) ----
#pragma unroll
        for (int r = 0; r < 4; r++)
            ztile_w[(quad * 4 + r) * 17 + l15] = acc[r];
        // compiler inserts lgkmcnt waits for the dependent ds_reads
        float zi = ztile_w[(quad * 4 + (l15 >> 2)) * 17 + 0  + (l15 & 3)];
        float zf = ztile_w[(quad * 4 + (l15 >> 2)) * 17 + 4  + (l15 & 3)];
        float zg = ztile_w[(quad * 4 + (l15 >> 2)) * 17 + 8  + (l15 & 3)];
        float zo = ztile_w[(quad * 4 + (l15 >> 2)) * 17 + 12 + (l15 & 3)];
        float si = 1.f / (1.f + __expf(-zi));
        float sf = 1.f / (1.f + __expf(-zf));
        float tg = tanhf(zg);
        float so = 1.f / (1.f + __expf(-zo));
        float nc = sf * c_reg + si * tg;
        float nh = so * tanhf(nc);
        c_reg = nc;
        hout_w[(quad * 4 + (l15 >> 2)) * 4 + (l15 & 3)] = f2bf(nh);

        // ---- publish h_t: wave-local 8B chunks as relaxed agent stores ----
        if (lane < 16) {
            ull v = *(const ull*)(hout_w + lane * 4);
            ull* dst = (ull*)(ring + (size_t)(t & 1) * 32768 +
                              blk * 512 + (mi * 16 + lane) * 8 + nt * 4);
            __hip_atomic_store(dst, v, __ATOMIC_RELAXED, __HIP_MEMORY_SCOPE_AGENT);
        }
        __syncthreads();   // B5: all ring stores drained (vmcnt(0) at barrier)
        if (tid == 0)
            __hip_atomic_store(&flag[blk * 8], (unsigned)(t + 1),
                               __ATOMIC_RELAXED, __HIP_MEMORY_SCOPE_AGENT);

        // ---- ys / final-state stores off the critical path ----
        out[(size_t)t * 32768 + crow * 512 + blk * 8 + ccol] = nh;
        if (t == T_STEPS - 1) {
            out[33554432u + crow * 512 + blk * 8 + ccol] = nc;           // cT
            out[33554432u + 32768u + crow * 512 + blk * 8 + ccol] = nh;  // hT
        }
    }
}

// ---------------------------------------------------------------------------
extern "C" void kernel_launch(void* const* d_in, const int* in_sizes, int n_in,
                              void* d_out, int out_size, void* d_ws, size_t ws_size,
                              hipStream_t stream) {
    const float* X    = (const float*)d_in[0];   // [1024][64][512]
    const float* c0   = (const float*)d_in[1];   // [64][512]
    const float* h0   = (const float*)d_in[2];   // [64][512]
    const float* Wi   = (const float*)d_in[3];   // [512][2048]
    const float* Wh   = (const float*)d_in[4];   // [512][2048]
    const float* bias = (const float*)d_in[5];   // [2048]

    char* ws = (char*)d_ws;
    ushort_t* WiT  = (ushort_t*)ws;                    // 2,097,152 B
    ushort_t* WhT  = (ushort_t*)(ws + 2097152);        // 2,097,152 B
    ushort_t* ring = (ushort_t*)(ws + 4194304);        //   131,072 B
    u32*      flag = (u32*)(ws + 4325376);             //     2,048 B
    // total ws need: 4,327,424 B

    lstm_setup<<<4161, NTHR, 0, stream>>>(Wi, Wh, h0, WiT, WhT, ring, flag);
    lstm_persist<<<NBLK, NTHR, 0, stream>>>(X, c0, bias, WiT, WhT, ring, flag,
                                            (float*)d_out);
}